// Round 7
// baseline (203.048 us; speedup 1.0000x reference)
//
#include <hip/hip_runtime.h>
#include <cstdint>

static constexpr int C     = 5;
static constexpr int MAXP  = 10;
static constexpr int MAXV  = 160000;
static constexpr int BLK   = 256;
static constexpr int RB    = 2048;         // hash buckets
static constexpr int BCAP  = 1024;         // bucket capacity (lambda~571 + guard)
static constexpr int EPT   = 8;
static constexpr int ELEMS = BLK * EPT;    // 2048 elements per block

// Output layout (float32, concatenated in reference return order)
static constexpr int VOX_OFF = 0;                           // 160000*10*5
static constexpr int CO_OFF  = MAXV * MAXP * C;             // 8,000,000
static constexpr int NPV_OFF = CO_OFF + MAXV * 3;           // 8,480,000
static constexpr int VN_OFF  = NPV_OFF + MAXV;              // 8,640,000

typedef unsigned long long u64;
static constexpr u64 BYTEMUL = 0x0101010101010101ull;

// Bucket partition: equal lins always share a bucket; inter-bucket order is
// irrelevant (vid comes from first-appearance rank via flags, not sort order).
__device__ __forceinline__ int hashb(int k) {
    return (int)(((uint32_t)k * 2654435761u) >> 21);        // 11 bits -> [0,2048)
}

// K1: quantize -> key0 (-1 = invalid), per-block bucket histogram; zero
// coors/npv (2.6 MB), flags8, ctrl. Voxel rows NOT zeroed here — final writes
// every kept row fully and tail-zeros [G,MAXV) (saves a 32 MB pass).
__global__ void vx_prep(const float* __restrict__ pts, const float* __restrict__ vsz,
                        const float* __restrict__ crg, int* __restrict__ key0,
                        int* __restrict__ hist, u64* __restrict__ flags8,
                        int* __restrict__ ctrl, float* __restrict__ out,
                        int NP, int NP8) {
    __shared__ int sh[RB];
    int t = threadIdx.x, b = blockIdx.x;
    for (int d = t; d < RB; d += BLK) sh[d] = 0;
    if (b == 0 && t < 8) ctrl[t] = 0;
    float vx = vsz[0], vy = vsz[1], vz = vsz[2];
    float x0 = crg[0], y0 = crg[1], z0 = crg[2];
    int gx = (int)rintf((crg[3] - x0) / vx);
    int gy = (int)rintf((crg[4] - y0) / vy);
    int gz = (int)rintf((crg[5] - z0) / vz);
    __syncthreads();
    int base = b * ELEMS;
    #pragma unroll
    for (int r = 0; r < EPT; r++) {
        int i = base + r * BLK + t;
        if (i < NP) {
            float px = pts[i * C], py = pts[i * C + 1], pz = pts[i * C + 2];
            int cx = (int)floorf((px - x0) / vx);
            int cy = (int)floorf((py - y0) / vy);
            int cz = (int)floorf((pz - z0) / vz);
            bool valid = (cx >= 0) & (cx < gx) & (cy >= 0) & (cy < gy) & (cz >= 0) & (cz < gz);
            int k = (cx * gy + cy) * gz + cz;
            key0[i] = valid ? k : -1;
            if (valid) atomicAdd(&sh[hashb(k)], 1);
        }
    }
    __syncthreads();
    for (int d = t; d < RB; d += BLK) hist[b * RB + d] = sh[d];
    // fused zero-fill: coors+npv region [CO_OFF, VN_OFF) + flags8
    int tid = b * BLK + t, nth = gridDim.x * BLK;
    float4* co4 = (float4*)(out + CO_OFF);
    const float4 z4 = make_float4(0.f, 0.f, 0.f, 0.f);
    const int nco4 = (VN_OFF - CO_OFF) / 4;                 // 160,000
    for (int i = tid; i < nco4; i += nth) co4[i] = z4;
    for (int i = tid; i < NP8; i += nth) flags8[i] = 0ull;
}

// K2: wave-per-bucket exclusive scan across blocks (grid = RB/4 = 512).
__global__ void vx_scanw(int* __restrict__ hist, int* __restrict__ dtot, int NB) {
    int t = threadIdx.x;
    int lane = t & 63;
    int d = blockIdx.x * 4 + (t >> 6);
    int carry = 0;
    for (int base = 0; base < NB; base += 64) {
        int b = base + lane;
        int v = (b < NB) ? hist[b * RB + d] : 0;
        int x = v;
        #pragma unroll
        for (int o = 1; o < 64; o <<= 1) {
            int y = __shfl_up(x, o, 64);
            if (lane >= o) x += y;
        }
        if (b < NB) hist[b * RB + d] = carry + x - v;        // exclusive
        carry += __shfl(x, 63, 64);
    }
    if (lane == 0) dtot[d] = carry;
}

// K3: UNSTABLE bucket scatter (LDS-atomic slot grab); publishes nval via one
// global atomic per block (586 total — cheap; 1M+ atomics was the r1 death).
__global__ void vx_scat(const int* __restrict__ key0, const int* __restrict__ hist,
                        const int* __restrict__ dtot, u64* __restrict__ pairA,
                        int* __restrict__ ctrl, int NP) {
    __shared__ int cnt[RB];
    __shared__ int svld;
    int t = threadIdx.x, b = blockIdx.x;
    int lane = t & 63;
    if (t == 0) svld = 0;
    if (t < 64) {                           // cross-bucket bases: 32 buckets/lane
        int loc[32]; int run = 0;
        #pragma unroll
        for (int j = 0; j < 32; j++) { loc[j] = run; run += dtot[t * 32 + j]; }
        int tot = run;
        for (int o = 1; o < 64; o <<= 1) {
            int x = __shfl_up(tot, o, 64);
            if (lane >= o) tot += x;
        }
        int excl = tot - run;
        #pragma unroll
        for (int j = 0; j < 32; j++) cnt[t * 32 + j] = excl + loc[j];
    }
    __syncthreads();
    for (int d = t; d < RB; d += BLK) cnt[d] += hist[b * RB + d];
    __syncthreads();
    int base = b * ELEMS;
    int myv = 0;
    #pragma unroll
    for (int r = 0; r < EPT; r++) {
        int i = base + r * BLK + t;
        if (i < NP) {
            int k = key0[i];
            if (k >= 0) {
                int pos = atomicAdd(&cnt[hashb(k)], 1);
                pairA[pos] = ((u64)(uint32_t)k << 32) | (uint32_t)i;
                myv++;
            }
        }
    }
    atomicAdd(&svld, myv);
    __syncthreads();
    if (t == 0) atomicAdd(&ctrl[1], svld);
}

// K4: hash-group + exact idx-rank -> 16B emission records (no pairA writeback,
// no emit-side LDS reconstruction). rec = {k, my_io, head_io, slot|gsz<<16}
// written at the element's grouped position (groups contiguous per bucket).
// rank-0 (min idx = head) sets the flags byte.
__global__ void __launch_bounds__(512) vx_group(const u64* __restrict__ pairA,
                                                const int* __restrict__ dtot,
                                                u64* __restrict__ flags8,
                                                uint4* __restrict__ recs) {
    __shared__ int htab[BCAP];          // keys -> fill ctr -> head-io (phased reuse)
    __shared__ int cnt[BCAP];           // per-slot count
    __shared__ int seg[BCAP];           // exclusive prefix (segment starts)
    __shared__ u64 sq[BCAP];            // multi-member segments (unordered)
    __shared__ int swp[8];              // per-wave scan partials
    __shared__ int sb[2];
    int t = threadIdx.x, d = blockIdx.x;
    if (t < 64) {                       // start = sum dtot[0..d)
        int acc = 0;
        for (int j = t; j < d; j += 64) acc += dtot[j];
        #pragma unroll
        for (int o = 32; o > 0; o >>= 1) acc += __shfl_down(acc, o, 64);
        if (t == 0) { sb[0] = acc; sb[1] = dtot[d]; }
    }
    for (int i = t; i < BCAP; i += 512) { htab[i] = -1; cnt[i] = 0; }
    __syncthreads();
    int start = sb[0], size = sb[1];
    if (size <= 0) return;              // uniform per block
    if (size > BCAP) size = BCAP;       // statistically unreachable guard
    bool a0 = t < size, a1 = t + 512 < size;
    u64 e0 = a0 ? pairA[start + t] : 0;
    u64 e1 = a1 ? pairA[start + 512 + t] : 0;
    int k0 = (int)(e0 >> 32), k1 = (int)(e1 >> 32);
    // hash-insert (open addressing; bounded probes: never hang)
    int s0 = 0, s1 = 0;
    if (a0) {
        s0 = (int)(((uint32_t)k0 * 0x85EBCA77u) >> 22);
        for (int it = 0; it < BCAP; ++it) {
            int old = atomicCAS(&htab[s0], -1, k0);
            if (old == -1 || old == k0) break;
            s0 = (s0 + 1) & (BCAP - 1);
        }
        atomicAdd(&cnt[s0], 1);
    }
    if (a1) {
        s1 = (int)(((uint32_t)k1 * 0x85EBCA77u) >> 22);
        for (int it = 0; it < BCAP; ++it) {
            int old = atomicCAS(&htab[s1], -1, k1);
            if (old == -1 || old == k1) break;
            s1 = (s1 + 1) & (BCAP - 1);
        }
        atomicAdd(&cnt[s1], 1);
    }
    __syncthreads();
    // exclusive scan of cnt[0..1023] -> seg (2 vals/thread, wave-scan + partials)
    int c0 = cnt[2 * t], c1 = cnt[2 * t + 1];
    int v = c0 + c1;
    int lane = t & 63, wv = t >> 6;
    int x = v;
    #pragma unroll
    for (int o = 1; o < 64; o <<= 1) {
        int y = __shfl_up(x, o, 64);
        if (lane >= o) x += y;
    }
    if (lane == 63) swp[wv] = x;
    // recycle htab as per-slot fill counters (all probes done)
    for (int i = t; i < BCAP; i += 512) htab[i] = 0;
    __syncthreads();
    if (t == 0) {
        int acc = 0;
        #pragma unroll
        for (int j = 0; j < 8; j++) { int tmp = swp[j]; swp[j] = acc; acc += tmp; }
    }
    __syncthreads();
    int excl = swp[wv] + x - v;
    seg[2 * t] = excl;
    seg[2 * t + 1] = excl + c0;
    __syncthreads();
    // scatter multi-member segments into sq (singletons skip: rank trivially 0)
    int st0 = 0, cn0 = 0, st1 = 0, cn1 = 0;
    if (a0) { st0 = seg[s0]; cn0 = cnt[s0]; if (cn0 > 1) sq[st0 + atomicAdd(&htab[s0], 1)] = e0; }
    if (a1) { st1 = seg[s1]; cn1 = cnt[s1]; if (cn1 > 1) sq[st1 + atomicAdd(&htab[s1], 1)] = e1; }
    __syncthreads();
    // exact rank within segment by idx; rank-0 publishes head io (htab reuse #2)
    int r0 = 0, r1 = 0;
    if (a0 && cn0 > 1) {
        uint32_t my = (uint32_t)e0;
        for (int q = st0; q < st0 + cn0; q++) r0 += ((uint32_t)sq[q] < my);
        if (r0 == 0) htab[s0] = (int)my;
    }
    if (a1 && cn1 > 1) {
        uint32_t my = (uint32_t)e1;
        for (int q = st1; q < st1 + cn1; q++) r1 += ((uint32_t)sq[q] < my);
        if (r1 == 0) htab[s1] = (int)my;
    }
    __syncthreads();
    unsigned char* flags = (unsigned char*)flags8;
    if (a0) {
        uint32_t my = (uint32_t)e0;
        uint32_t head = (cn0 > 1) ? (uint32_t)htab[s0] : my;
        if (r0 == 0) flags[my] = 1;
        recs[start + st0 + r0] =
            make_uint4((uint32_t)k0, my, head, (uint32_t)r0 | ((uint32_t)cn0 << 16));
    }
    if (a1) {
        uint32_t my = (uint32_t)e1;
        uint32_t head = (cn1 > 1) ? (uint32_t)htab[s1] : my;
        if (r1 == 0) flags[my] = 1;
        recs[start + st1 + r1] =
            make_uint4((uint32_t)k1, my, head, (uint32_t)r1 | ((uint32_t)cn1 << 16));
    }
}

// K5: per-block bytesum of flag words (publishes partials for wp2's walk).
__global__ void vx_wpA(const u64* __restrict__ flags8, int* __restrict__ wsum, int NP8) {
    __shared__ int s[BLK];
    int t = threadIdx.x, i = blockIdx.x * BLK + t;
    u64 wv = (i < NP8) ? flags8[i] : 0ull;
    s[t] = (int)((wv * BYTEMUL) >> 56);
    __syncthreads();
    for (int o = BLK / 2; o > 0; o >>= 1) { if (t < o) s[t] += s[t + o]; __syncthreads(); }
    if (t == 0) wsum[blockIdx.x] = s[0];
}

// K6: no-spin walk over wsum + in-block scan -> wpfx; last block publishes
// G_kept (ctrl[0]) + voxel_num.
__global__ void vx_wp2(const u64* __restrict__ flags8, const int* __restrict__ wsum,
                       int* __restrict__ wpfx, int* __restrict__ ctrl,
                       float* __restrict__ out_vnum, int NP8) {
    __shared__ int s[BLK];
    __shared__ int eS;
    int t = threadIdx.x, b = blockIdx.x;
    if (t < 64) {
        int acc = 0;
        for (int base = 0; base < b; base += 64) {
            int idx = base + t;
            int v = (idx < b) ? wsum[idx] : 0;
            #pragma unroll
            for (int o = 32; o > 0; o >>= 1) v += __shfl_down(v, o, 64);
            acc += v;
        }
        if (t == 0) eS = acc;
    }
    int i = b * BLK + t;
    u64 wv = (i < NP8) ? flags8[i] : 0ull;
    int v = (int)((wv * BYTEMUL) >> 56);
    s[t] = v;
    __syncthreads();                        // also publishes eS
    for (int o = 1; o < BLK; o <<= 1) {
        int x = (t >= o) ? s[t - o] : 0; __syncthreads();
        s[t] += x; __syncthreads();
    }
    if (i < NP8) wpfx[i] = eS + s[t] - v;
    if (b == gridDim.x - 1 && t == BLK - 1) {
        int G = eS + s[t];
        int Gk = G < MAXV ? G : MAXV;
        ctrl[0] = Gk;
        out_vnum[0] = (float)Gk;
    }
}

__device__ __forceinline__ int vox_rank(const u64* flags8, const int* wpfx, int io) {
    int w = io >> 3, b8 = io & 7;
    u64 below = flags8[w] & ((1ull << (8 * b8)) - 1ull);
    return wpfx[w] + (int)((below * BYTEMUL) >> 56);
}

// K7: streaming final — coalesced record reads, no LDS, no barriers. Each
// record writes its own 20B; head records also write coors/npv and zero-fill
// unused slots of the row (full row coverage for vid < G_kept). Tail rows
// [G_kept, MAXV) zeroed grid-stride (replaces the old 32 MB blind zero).
__global__ void vx_final(const uint4* __restrict__ recs, const u64* __restrict__ flags8,
                         const int* __restrict__ wpfx, const int* __restrict__ ctrl,
                         const float* __restrict__ pts, const float* __restrict__ vsz,
                         const float* __restrict__ crg, float* __restrict__ out, int NP) {
    int t = threadIdx.x, b = blockIdx.x;
    int nval = ctrl[1], Gk = ctrl[0];
    int gyd = (int)rintf((crg[4] - crg[1]) / vsz[1]);
    int gzd = (int)rintf((crg[5] - crg[2]) / vsz[2]);
    int base = b * ELEMS;
    #pragma unroll
    for (int r = 0; r < EPT; r++) {
        int i = base + r * BLK + t;
        if (i >= nval) continue;
        uint4 rec = recs[i];
        int k = (int)rec.x;
        uint32_t my = rec.y, head = rec.z;
        int slot = (int)(rec.w & 0xFFFFu);
        int gsz  = (int)(rec.w >> 16);
        // guards also protect against poison reads in the (statistically
        // unreachable) BCAP-truncation case
        if (slot >= MAXP || head >= (uint32_t)NP || my >= (uint32_t)NP) continue;
        int vid = vox_rank(flags8, wpfx, (int)head);
        if (vid >= MAXV) continue;
        const float* src = pts + my * C;
        float* dst = out + (vid * MAXP + slot) * C;
        dst[0] = src[0]; dst[1] = src[1]; dst[2] = src[2]; dst[3] = src[3]; dst[4] = src[4];
        if (slot == 0) {                    // once per kept voxel
            int cz = k % gzd; int rr = k / gzd; int cy = rr % gyd; int cx = rr / gyd;
            out[CO_OFF + vid * 3 + 0] = (float)cz;
            out[CO_OFF + vid * 3 + 1] = (float)cy;
            out[CO_OFF + vid * 3 + 2] = (float)cx;
            int np = gsz < MAXP ? gsz : MAXP;
            out[NPV_OFF + vid] = (float)np;
            float* rowz = out + (vid * MAXP + np) * C;
            int nz = (MAXP - np) * C;
            for (int z = 0; z < nz; z++) rowz[z] = 0.f;     // unused slots
        }
    }
    // tail rows [Gk, MAXV): never touched by records; zero grid-stride.
    int nz2 = (MAXV - Gk) * (MAXP * C) / 2;                 // float2 count (50 even)
    if (nz2 > 0) {
        float2* z2 = (float2*)(out + Gk * MAXP * C);
        const float2 zz = make_float2(0.f, 0.f);
        int tid = b * BLK + t, nth = gridDim.x * BLK;
        for (int i = tid; i < nz2; i += nth) z2[i] = zz;
    }
}

extern "C" void kernel_launch(void* const* d_in, const int* in_sizes, int n_in,
                              void* d_out, int out_size, void* d_ws, size_t ws_size,
                              hipStream_t stream) {
    if (!d_out || !d_ws || n_in < 3) return;
    const float* pts = (const float*)d_in[0];
    const float* vsz = (const float*)d_in[1];
    const float* crg = (const float*)d_in[2];
    if (!pts || !vsz || !crg) return;
    const int NP  = in_sizes[0] / C;
    if (NP <= 0) return;
    const int NB  = (NP + ELEMS - 1) / ELEMS;     // 2048-elem blocks (586)
    const int NP8 = (NP + 7) / 8;                 // byte-flag u64 words (150000)
    const int NWB = (NP8 + BLK - 1) / BLK;        // wp blocks (586)

    size_t need = (size_t)NP * 8ull                         // pairA
                + (size_t)NP * 16ull                        // recs
                + (size_t)NP * 4ull                         // key0
                + (size_t)RB * NB * 4ull                    // hist
                + (size_t)RB * 4ull                         // dtot
                + (size_t)NP8 * 8ull                        // flags8
                + (size_t)NP8 * 4ull                        // wpfx
                + (size_t)NWB * 4ull + 64ull;               // wsum + ctrl + pad
    if (ws_size < need) return;
    if ((size_t)out_size < (size_t)VN_OFF + 1) return;

    u64*   pairA  = (u64*)d_ws;
    uint4* recs   = (uint4*)(pairA + NP);         // 16B-aligned (NP even)
    int*   key0   = (int*)(recs + NP);
    int*   hist   = key0 + NP;
    int*   dtot   = hist + (size_t)RB * NB;
    u64*   flags8 = (u64*)(dtot + RB);            // 8B-aligned
    int*   wpfx   = (int*)(flags8 + NP8);
    int*   wsum   = wpfx + NP8;
    int*   ctrl   = wsum + NWB;
    float* out    = (float*)d_out;

    vx_prep<<<NB, BLK, 0, stream>>>(pts, vsz, crg, key0, hist, flags8, ctrl, out, NP, NP8);
    vx_scanw<<<RB / 4, BLK, 0, stream>>>(hist, dtot, NB);
    vx_scat<<<NB, BLK, 0, stream>>>(key0, hist, dtot, pairA, ctrl, NP);
    vx_group<<<RB, 512, 0, stream>>>(pairA, dtot, flags8, recs);
    vx_wpA<<<NWB, BLK, 0, stream>>>(flags8, wsum, NP8);
    vx_wp2<<<NWB, BLK, 0, stream>>>(flags8, wsum, wpfx, ctrl, out + VN_OFF, NP8);
    vx_final<<<NB, BLK, 0, stream>>>(recs, flags8, wpfx, ctrl, pts, vsz, crg, out, NP);
}

// Round 8
// 179.252 us; speedup vs baseline: 1.1327x; 1.1327x over previous
//
#include <hip/hip_runtime.h>
#include <cstdint>

static constexpr int C     = 5;
static constexpr int MAXP  = 10;
static constexpr int MAXV  = 160000;
static constexpr int BLK   = 256;
static constexpr int RB    = 2048;         // hash buckets
static constexpr int BCAP  = 1024;         // bucket capacity (lambda~571 + guard)
static constexpr int EPT   = 8;
static constexpr int ELEMS = BLK * EPT;    // 2048 elements per block

// Output layout (float32, concatenated in reference return order)
static constexpr int VOX_OFF = 0;                           // 160000*10*5
static constexpr int CO_OFF  = MAXV * MAXP * C;             // 8,000,000
static constexpr int NPV_OFF = CO_OFF + MAXV * 3;           // 8,480,000
static constexpr int VN_OFF  = NPV_OFF + MAXV;              // 8,640,000

typedef unsigned long long u64;
static constexpr u64 BYTEMUL = 0x0101010101010101ull;

// Compact 8B record (r7's 16B uint4 halved; fields sized for NP<2^25, k<2^27):
//  head:     bit63=1 | gsz(min(cn,15))[55:52] | k[51:25] | my[24:0]
//  non-head: bit63=0 | slot(min(r,15))[53:50] | head_io[49:25] | my[24:0]
// slot>=MAXP and truncation-poison are skipped in final via guards.

// Bucket partition: equal lins always share a bucket; inter-bucket order is
// irrelevant (vid comes from first-appearance rank via flags, not order).
__device__ __forceinline__ int hashb(int k) {
    return (int)(((uint32_t)k * 2654435761u) >> 21);        // 11 bits -> [0,2048)
}

// K1: quantize -> key0 (-1 = invalid), per-block bucket histogram; fused BLIND
// zero of the whole output block + flags8 (contiguous float4 = near-HBM-peak;
// r7 re-proved that scattering this zero into the emit path costs ~2.5x).
__global__ void vx_prep(const float* __restrict__ pts, const float* __restrict__ vsz,
                        const float* __restrict__ crg, int* __restrict__ key0,
                        int* __restrict__ hist, u64* __restrict__ flags8,
                        int* __restrict__ ctrl, float* __restrict__ out,
                        int NP, int NP8) {
    __shared__ int sh[RB];
    int t = threadIdx.x, b = blockIdx.x;
    for (int d = t; d < RB; d += BLK) sh[d] = 0;
    if (b == 0 && t < 8) ctrl[t] = 0;
    float vx = vsz[0], vy = vsz[1], vz = vsz[2];
    float x0 = crg[0], y0 = crg[1], z0 = crg[2];
    int gx = (int)rintf((crg[3] - x0) / vx);
    int gy = (int)rintf((crg[4] - y0) / vy);
    int gz = (int)rintf((crg[5] - z0) / vz);
    __syncthreads();
    int base = b * ELEMS;
    #pragma unroll
    for (int r = 0; r < EPT; r++) {
        int i = base + r * BLK + t;
        if (i < NP) {
            float px = pts[i * C], py = pts[i * C + 1], pz = pts[i * C + 2];
            int cx = (int)floorf((px - x0) / vx);
            int cy = (int)floorf((py - y0) / vy);
            int cz = (int)floorf((pz - z0) / vz);
            bool valid = (cx >= 0) & (cx < gx) & (cy >= 0) & (cy < gy) & (cz >= 0) & (cz < gz);
            int k = (cx * gy + cy) * gz + cz;
            key0[i] = valid ? k : -1;
            if (valid) atomicAdd(&sh[hashb(k)], 1);
        }
    }
    __syncthreads();
    for (int d = t; d < RB; d += BLK) hist[b * RB + d] = sh[d];
    // fused zero-fill: voxels + coors + npv + flags8
    int tid = b * BLK + t, nth = gridDim.x * BLK;
    float4* out4 = (float4*)out;
    const float4 z4 = make_float4(0.f, 0.f, 0.f, 0.f);
    for (int i = tid; i < VN_OFF / 4; i += nth) out4[i] = z4;
    for (int i = tid; i < NP8; i += nth) flags8[i] = 0ull;
}

// K2: wave-per-bucket exclusive scan across blocks (grid = RB/4 = 512).
__global__ void vx_scanw(int* __restrict__ hist, int* __restrict__ dtot, int NB) {
    int t = threadIdx.x;
    int lane = t & 63;
    int d = blockIdx.x * 4 + (t >> 6);
    int carry = 0;
    for (int base = 0; base < NB; base += 64) {
        int b = base + lane;
        int v = (b < NB) ? hist[b * RB + d] : 0;
        int x = v;
        #pragma unroll
        for (int o = 1; o < 64; o <<= 1) {
            int y = __shfl_up(x, o, 64);
            if (lane >= o) x += y;
        }
        if (b < NB) hist[b * RB + d] = carry + x - v;        // exclusive
        carry += __shfl(x, 63, 64);
    }
    if (lane == 0) dtot[d] = carry;
}

// K3: UNSTABLE bucket scatter (LDS-atomic slot grab); publishes nval via one
// global atomic per block (586 total — cheap; 1M+ atomics was the r1 death).
__global__ void vx_scat(const int* __restrict__ key0, const int* __restrict__ hist,
                        const int* __restrict__ dtot, u64* __restrict__ pairA,
                        int* __restrict__ ctrl, int NP) {
    __shared__ int cnt[RB];
    __shared__ int svld;
    int t = threadIdx.x, b = blockIdx.x;
    int lane = t & 63;
    if (t == 0) svld = 0;
    if (t < 64) {                           // cross-bucket bases: 32 buckets/lane
        int loc[32]; int run = 0;
        #pragma unroll
        for (int j = 0; j < 32; j++) { loc[j] = run; run += dtot[t * 32 + j]; }
        int tot = run;
        for (int o = 1; o < 64; o <<= 1) {
            int x = __shfl_up(tot, o, 64);
            if (lane >= o) tot += x;
        }
        int excl = tot - run;
        #pragma unroll
        for (int j = 0; j < 32; j++) cnt[t * 32 + j] = excl + loc[j];
    }
    __syncthreads();
    for (int d = t; d < RB; d += BLK) cnt[d] += hist[b * RB + d];
    __syncthreads();
    int base = b * ELEMS;
    int myv = 0;
    #pragma unroll
    for (int r = 0; r < EPT; r++) {
        int i = base + r * BLK + t;
        if (i < NP) {
            int k = key0[i];
            if (k >= 0) {
                int pos = atomicAdd(&cnt[hashb(k)], 1);
                pairA[pos] = ((u64)(uint32_t)k << 32) | (uint32_t)i;
                myv++;
            }
        }
    }
    atomicAdd(&svld, myv);
    __syncthreads();
    if (t == 0) atomicAdd(&ctrl[1], svld);
}

// K4: hash-group + exact idx-rank -> compact 8B records. rank-0 (min idx =
// head) sets the flags byte. No pairA writeback.
__global__ void __launch_bounds__(512) vx_group(const u64* __restrict__ pairA,
                                                const int* __restrict__ dtot,
                                                u64* __restrict__ flags8,
                                                u64* __restrict__ recs) {
    __shared__ int htab[BCAP];          // keys -> fill ctr -> head-io (phased reuse)
    __shared__ int cnt[BCAP];           // per-slot count
    __shared__ int seg[BCAP];           // exclusive prefix (segment starts)
    __shared__ u64 sq[BCAP];            // multi-member segments (unordered)
    __shared__ int swp[8];              // per-wave scan partials
    __shared__ int sb[2];
    int t = threadIdx.x, d = blockIdx.x;
    if (t < 64) {                       // start = sum dtot[0..d)
        int acc = 0;
        for (int j = t; j < d; j += 64) acc += dtot[j];
        #pragma unroll
        for (int o = 32; o > 0; o >>= 1) acc += __shfl_down(acc, o, 64);
        if (t == 0) { sb[0] = acc; sb[1] = dtot[d]; }
    }
    for (int i = t; i < BCAP; i += 512) { htab[i] = -1; cnt[i] = 0; }
    __syncthreads();
    int start = sb[0], size = sb[1];
    if (size <= 0) return;              // uniform per block
    if (size > BCAP) size = BCAP;       // statistically unreachable guard
    bool a0 = t < size, a1 = t + 512 < size;
    u64 e0 = a0 ? pairA[start + t] : 0;
    u64 e1 = a1 ? pairA[start + 512 + t] : 0;
    int k0 = (int)(e0 >> 32), k1 = (int)(e1 >> 32);
    // hash-insert (open addressing; bounded probes: never hang)
    int s0 = 0, s1 = 0;
    if (a0) {
        s0 = (int)(((uint32_t)k0 * 0x85EBCA77u) >> 22);
        for (int it = 0; it < BCAP; ++it) {
            int old = atomicCAS(&htab[s0], -1, k0);
            if (old == -1 || old == k0) break;
            s0 = (s0 + 1) & (BCAP - 1);
        }
        atomicAdd(&cnt[s0], 1);
    }
    if (a1) {
        s1 = (int)(((uint32_t)k1 * 0x85EBCA77u) >> 22);
        for (int it = 0; it < BCAP; ++it) {
            int old = atomicCAS(&htab[s1], -1, k1);
            if (old == -1 || old == k1) break;
            s1 = (s1 + 1) & (BCAP - 1);
        }
        atomicAdd(&cnt[s1], 1);
    }
    __syncthreads();
    // exclusive scan of cnt[0..1023] -> seg (2 vals/thread, wave-scan + partials)
    int c0 = cnt[2 * t], c1 = cnt[2 * t + 1];
    int v = c0 + c1;
    int lane = t & 63, wv = t >> 6;
    int x = v;
    #pragma unroll
    for (int o = 1; o < 64; o <<= 1) {
        int y = __shfl_up(x, o, 64);
        if (lane >= o) x += y;
    }
    if (lane == 63) swp[wv] = x;
    // recycle htab as per-slot fill counters (all probes done)
    for (int i = t; i < BCAP; i += 512) htab[i] = 0;
    __syncthreads();
    if (t == 0) {
        int acc = 0;
        #pragma unroll
        for (int j = 0; j < 8; j++) { int tmp = swp[j]; swp[j] = acc; acc += tmp; }
    }
    __syncthreads();
    int excl = swp[wv] + x - v;
    seg[2 * t] = excl;
    seg[2 * t + 1] = excl + c0;
    __syncthreads();
    // scatter multi-member segments into sq (singletons skip: rank trivially 0)
    int st0 = 0, cn0 = 0, st1 = 0, cn1 = 0;
    if (a0) { st0 = seg[s0]; cn0 = cnt[s0]; if (cn0 > 1) sq[st0 + atomicAdd(&htab[s0], 1)] = e0; }
    if (a1) { st1 = seg[s1]; cn1 = cnt[s1]; if (cn1 > 1) sq[st1 + atomicAdd(&htab[s1], 1)] = e1; }
    __syncthreads();
    // exact rank within segment by idx; rank-0 publishes head io (htab reuse #2)
    int r0 = 0, r1 = 0;
    if (a0 && cn0 > 1) {
        uint32_t my = (uint32_t)e0;
        for (int q = st0; q < st0 + cn0; q++) r0 += ((uint32_t)sq[q] < my);
        if (r0 == 0) htab[s0] = (int)my;
    }
    if (a1 && cn1 > 1) {
        uint32_t my = (uint32_t)e1;
        for (int q = st1; q < st1 + cn1; q++) r1 += ((uint32_t)sq[q] < my);
        if (r1 == 0) htab[s1] = (int)my;
    }
    __syncthreads();
    unsigned char* flags = (unsigned char*)flags8;
    if (a0) {
        uint32_t my = (uint32_t)e0;
        u64 rec;
        if (r0 == 0) {
            flags[my] = 1;
            int g = cn0 < 15 ? cn0 : 15;
            rec = (1ull << 63) | ((u64)g << 52) | ((u64)(uint32_t)k0 << 25) | my;
        } else {
            uint32_t head = (uint32_t)htab[s0];
            int sl = r0 < 15 ? r0 : 15;
            rec = ((u64)sl << 50) | ((u64)head << 25) | my;
        }
        recs[start + st0 + r0] = rec;
    }
    if (a1) {
        uint32_t my = (uint32_t)e1;
        u64 rec;
        if (r1 == 0) {
            flags[my] = 1;
            int g = cn1 < 15 ? cn1 : 15;
            rec = (1ull << 63) | ((u64)g << 52) | ((u64)(uint32_t)k1 << 25) | my;
        } else {
            uint32_t head = (uint32_t)htab[s1];
            int sl = r1 < 15 ? r1 : 15;
            rec = ((u64)sl << 50) | ((u64)head << 25) | my;
        }
        recs[start + st1 + r1] = rec;
    }
}

// K5: per-block bytesum of flag words (publishes partials for wp2's walk).
__global__ void vx_wpA(const u64* __restrict__ flags8, int* __restrict__ wsum, int NP8) {
    __shared__ int s[BLK];
    int t = threadIdx.x, i = blockIdx.x * BLK + t;
    u64 wv = (i < NP8) ? flags8[i] : 0ull;
    s[t] = (int)((wv * BYTEMUL) >> 56);
    __syncthreads();
    for (int o = BLK / 2; o > 0; o >>= 1) { if (t < o) s[t] += s[t + o]; __syncthreads(); }
    if (t == 0) wsum[blockIdx.x] = s[0];
}

// K6: no-spin walk over wsum + in-block scan -> wpfx; last block publishes vnum.
__global__ void vx_wp2(const u64* __restrict__ flags8, const int* __restrict__ wsum,
                       int* __restrict__ wpfx, float* __restrict__ out_vnum, int NP8) {
    __shared__ int s[BLK];
    __shared__ int eS;
    int t = threadIdx.x, b = blockIdx.x;
    if (t < 64) {
        int acc = 0;
        for (int base = 0; base < b; base += 64) {
            int idx = base + t;
            int v = (idx < b) ? wsum[idx] : 0;
            #pragma unroll
            for (int o = 32; o > 0; o >>= 1) v += __shfl_down(v, o, 64);
            acc += v;
        }
        if (t == 0) eS = acc;
    }
    int i = b * BLK + t;
    u64 wv = (i < NP8) ? flags8[i] : 0ull;
    int v = (int)((wv * BYTEMUL) >> 56);
    s[t] = v;
    __syncthreads();                        // also publishes eS
    for (int o = 1; o < BLK; o <<= 1) {
        int x = (t >= o) ? s[t - o] : 0; __syncthreads();
        s[t] += x; __syncthreads();
    }
    if (i < NP8) wpfx[i] = eS + s[t] - v;
    if (b == gridDim.x - 1 && t == BLK - 1) {
        int G = eS + s[t];
        out_vnum[0] = (float)(G < MAXV ? G : MAXV);
    }
}

__device__ __forceinline__ int vox_rank(const u64* flags8, const int* wpfx, int io) {
    int w = io >> 3, b8 = io & 7;
    u64 below = flags8[w] & ((1ull << (8 * b8)) - 1ull);
    return wpfx[w] + (int)((below * BYTEMUL) >> 56);
}

// K7: streaming final — coalesced 8B record reads, no LDS, no barriers, no
// zeroing (prep's blind fill covers all untouched bytes). EPT=2 + 2x grid for
// latency hiding of the pts gather / out scatter.
static constexpr int EPTF = 2;
__global__ void vx_final(const u64* __restrict__ recs, const u64* __restrict__ flags8,
                         const int* __restrict__ wpfx, const int* __restrict__ ctrl,
                         const float* __restrict__ pts, const float* __restrict__ vsz,
                         const float* __restrict__ crg, float* __restrict__ out, int NP) {
    int t = threadIdx.x, b = blockIdx.x;
    int nval = ctrl[1];
    int gyd = (int)rintf((crg[4] - crg[1]) / vsz[1]);
    int gzd = (int)rintf((crg[5] - crg[2]) / vsz[2]);
    int base = b * (BLK * EPTF);
    #pragma unroll
    for (int r = 0; r < EPTF; r++) {
        int i = base + r * BLK + t;
        if (i >= nval) continue;
        u64 rec = recs[i];
        uint32_t my = (uint32_t)(rec & 0x1FFFFFFu);
        bool ishead = (rec >> 63) != 0;
        uint32_t head;
        int slot, k = 0, gsz = 0;
        if (ishead) {
            head = my; slot = 0;
            k = (int)((rec >> 25) & 0x7FFFFFFu);
            gsz = (int)((rec >> 52) & 15u);
        } else {
            head = (uint32_t)((rec >> 25) & 0x1FFFFFFu);
            slot = (int)((rec >> 50) & 15u);
        }
        // guards also cover poison reads in the (statistically unreachable)
        // BCAP-truncation case
        if (slot >= MAXP || my >= (uint32_t)NP || head >= (uint32_t)NP) continue;
        int vid = vox_rank(flags8, wpfx, (int)head);
        if (vid >= MAXV) continue;
        const float* src = pts + my * C;
        float* dst = out + (vid * MAXP + slot) * C;
        dst[0] = src[0]; dst[1] = src[1]; dst[2] = src[2]; dst[3] = src[3]; dst[4] = src[4];
        if (ishead) {
            int cz = k % gzd; int rr = k / gzd; int cy = rr % gyd; int cx = rr / gyd;
            out[CO_OFF + vid * 3 + 0] = (float)cz;
            out[CO_OFF + vid * 3 + 1] = (float)cy;
            out[CO_OFF + vid * 3 + 2] = (float)cx;
            out[NPV_OFF + vid] = (float)(gsz < MAXP ? gsz : MAXP);
        }
    }
}

extern "C" void kernel_launch(void* const* d_in, const int* in_sizes, int n_in,
                              void* d_out, int out_size, void* d_ws, size_t ws_size,
                              hipStream_t stream) {
    if (!d_out || !d_ws || n_in < 3) return;
    const float* pts = (const float*)d_in[0];
    const float* vsz = (const float*)d_in[1];
    const float* crg = (const float*)d_in[2];
    if (!pts || !vsz || !crg) return;
    const int NP  = in_sizes[0] / C;
    if (NP <= 0 || NP >= (1 << 25)) return;       // record io-field width
    const int NB  = (NP + ELEMS - 1) / ELEMS;     // 2048-elem blocks (586)
    const int NP8 = (NP + 7) / 8;                 // byte-flag u64 words (150000)
    const int NWB = (NP8 + BLK - 1) / BLK;        // wp blocks (586)
    const int NBF = (NP + BLK * EPTF - 1) / (BLK * EPTF);   // final blocks (2344)

    size_t need = (size_t)NP * 8ull                         // pairA
                + (size_t)NP * 8ull                         // recs
                + (size_t)NP * 4ull                         // key0
                + (size_t)RB * NB * 4ull                    // hist
                + (size_t)RB * 4ull                         // dtot
                + (size_t)NP8 * 8ull                        // flags8
                + (size_t)NP8 * 4ull                        // wpfx
                + (size_t)NWB * 4ull + 64ull;               // wsum + ctrl + pad
    if (ws_size < need) return;
    if ((size_t)out_size < (size_t)VN_OFF + 1) return;

    u64*   pairA  = (u64*)d_ws;
    u64*   recs   = pairA + NP;
    int*   key0   = (int*)(recs + NP);
    int*   hist   = key0 + NP;
    int*   dtot   = hist + (size_t)RB * NB;
    u64*   flags8 = (u64*)(dtot + RB);            // 8B-aligned
    int*   wpfx   = (int*)(flags8 + NP8);
    int*   wsum   = wpfx + NP8;
    int*   ctrl   = wsum + NWB;
    float* out    = (float*)d_out;

    vx_prep<<<NB, BLK, 0, stream>>>(pts, vsz, crg, key0, hist, flags8, ctrl, out, NP, NP8);
    vx_scanw<<<RB / 4, BLK, 0, stream>>>(hist, dtot, NB);
    vx_scat<<<NB, BLK, 0, stream>>>(key0, hist, dtot, pairA, ctrl, NP);
    vx_group<<<RB, 512, 0, stream>>>(pairA, dtot, flags8, recs);
    vx_wpA<<<NWB, BLK, 0, stream>>>(flags8, wsum, NP8);
    vx_wp2<<<NWB, BLK, 0, stream>>>(flags8, wsum, wpfx, out + VN_OFF, NP8);
    vx_final<<<NBF, BLK, 0, stream>>>(recs, flags8, wpfx, ctrl, pts, vsz, crg, out, NP);
}

// Round 9
// 175.988 us; speedup vs baseline: 1.1538x; 1.0185x over previous
//
#include <hip/hip_runtime.h>
#include <cstdint>

static constexpr int C     = 5;
static constexpr int MAXP  = 10;
static constexpr int MAXV  = 160000;
static constexpr int BLK   = 256;
static constexpr int RB    = 2048;         // hash buckets
static constexpr int BCAP  = 1024;         // bucket capacity (lambda~571 + guard)
static constexpr int EPT   = 8;
static constexpr int ELEMS = BLK * EPT;    // 2048 elements per block

// Output layout (float32, concatenated in reference return order)
static constexpr int VOX_OFF = 0;                           // 160000*10*5
static constexpr int CO_OFF  = MAXV * MAXP * C;             // 8,000,000
static constexpr int NPV_OFF = CO_OFF + MAXV * 3;           // 8,480,000
static constexpr int VN_OFF  = NPV_OFF + MAXV;              // 8,640,000

typedef unsigned long long u64;
static constexpr u64 BYTEMUL = 0x0101010101010101ull;

// Compact 8B record (fields sized for NP<2^25, k<2^27):
//  head:     bit63=1 | gsz(min(cn,15))[55:52] | k[51:25] | my[24:0]
//  non-head: bit63=0 | slot(min(r,15))[53:50] | head_io[49:25] | my[24:0]

// Bucket partition: equal lins always share a bucket; inter-bucket order is
// irrelevant (vid comes from first-appearance rank via flags, not order).
__device__ __forceinline__ int hashb(int k) {
    return (int)(((uint32_t)k * 2654435761u) >> 21);        // 11 bits -> [0,2048)
}

// K1: quantize -> key0 (-1 = invalid), per-block bucket histogram; fused BLIND
// zero of the whole output block + flags8 (contiguous float4 = near-HBM-peak;
// r7 re-proved that scattering this zero into the emit path costs ~2.5x).
// pts staged via coalesced float4 -> LDS (G13: 3 scalar 20B-strided loads are
// the classic anti-pattern). ctrl[2] init = INT_MAX (io*, set by wp2).
__global__ void vx_prep(const float* __restrict__ pts, const float* __restrict__ vsz,
                        const float* __restrict__ crg, int* __restrict__ key0,
                        int* __restrict__ hist, u64* __restrict__ flags8,
                        int* __restrict__ ctrl, float* __restrict__ out,
                        int NP, int NP8) {
    __shared__ int sh[RB];                  // 8 KB
    __shared__ float spts[ELEMS * C];       // 40 KB staged points
    int t = threadIdx.x, b = blockIdx.x;
    for (int d = t; d < RB; d += BLK) sh[d] = 0;
    if (b == 0 && t < 8) ctrl[t] = (t == 2) ? 0x7FFFFFFF : 0;
    float vx = vsz[0], vy = vsz[1], vz = vsz[2];
    float x0 = crg[0], y0 = crg[1], z0 = crg[2];
    int gx = (int)rintf((crg[3] - x0) / vx);
    int gy = (int)rintf((crg[4] - y0) / vy);
    int gz = (int)rintf((crg[5] - z0) / vz);
    // coalesced float4 staging (block chunk = 2048 pts * 20 B = 40960 B, 16-aligned)
    int nfl = NP * C;
    int basef = b * (ELEMS * C);
    for (int i4 = t; i4 < (ELEMS * C) / 4; i4 += BLK) {
        int gf = basef + i4 * 4;
        float4 v4;
        if (gf + 4 <= nfl) v4 = *(const float4*)(pts + gf);
        else {
            v4.x = (gf + 0 < nfl) ? pts[gf + 0] : 0.f;
            v4.y = (gf + 1 < nfl) ? pts[gf + 1] : 0.f;
            v4.z = (gf + 2 < nfl) ? pts[gf + 2] : 0.f;
            v4.w = 0.f;
        }
        *(float4*)(spts + i4 * 4) = v4;
    }
    __syncthreads();
    int base = b * ELEMS;
    #pragma unroll
    for (int r = 0; r < EPT; r++) {
        int li = r * BLK + t, i = base + li;
        if (i < NP) {
            float px = spts[li * C], py = spts[li * C + 1], pz = spts[li * C + 2];
            int cx = (int)floorf((px - x0) / vx);
            int cy = (int)floorf((py - y0) / vy);
            int cz = (int)floorf((pz - z0) / vz);
            bool valid = (cx >= 0) & (cx < gx) & (cy >= 0) & (cy < gy) & (cz >= 0) & (cz < gz);
            int k = (cx * gy + cy) * gz + cz;
            key0[i] = valid ? k : -1;
            if (valid) atomicAdd(&sh[hashb(k)], 1);
        }
    }
    __syncthreads();
    for (int d = t; d < RB; d += BLK) hist[b * RB + d] = sh[d];
    // fused zero-fill: voxels + coors + npv + flags8
    int tid = b * BLK + t, nth = gridDim.x * BLK;
    float4* out4 = (float4*)out;
    const float4 z4 = make_float4(0.f, 0.f, 0.f, 0.f);
    for (int i = tid; i < VN_OFF / 4; i += nth) out4[i] = z4;
    for (int i = tid; i < NP8; i += nth) flags8[i] = 0ull;
}

// K2: wave-per-bucket exclusive scan across blocks (grid = RB/4 = 512).
__global__ void vx_scanw(int* __restrict__ hist, int* __restrict__ dtot, int NB) {
    int t = threadIdx.x;
    int lane = t & 63;
    int d = blockIdx.x * 4 + (t >> 6);
    int carry = 0;
    for (int base = 0; base < NB; base += 64) {
        int b = base + lane;
        int v = (b < NB) ? hist[b * RB + d] : 0;
        int x = v;
        #pragma unroll
        for (int o = 1; o < 64; o <<= 1) {
            int y = __shfl_up(x, o, 64);
            if (lane >= o) x += y;
        }
        if (b < NB) hist[b * RB + d] = carry + x - v;        // exclusive
        carry += __shfl(x, 63, 64);
    }
    if (lane == 0) dtot[d] = carry;
}

// K3: UNSTABLE bucket scatter (LDS-atomic slot grab); publishes nval via one
// global atomic per block (586 total — cheap; 1M+ atomics was the r1 death).
__global__ void vx_scat(const int* __restrict__ key0, const int* __restrict__ hist,
                        const int* __restrict__ dtot, u64* __restrict__ pairA,
                        int* __restrict__ ctrl, int NP) {
    __shared__ int cnt[RB];
    __shared__ int svld;
    int t = threadIdx.x, b = blockIdx.x;
    int lane = t & 63;
    if (t == 0) svld = 0;
    if (t < 64) {                           // cross-bucket bases: 32 buckets/lane
        int loc[32]; int run = 0;
        #pragma unroll
        for (int j = 0; j < 32; j++) { loc[j] = run; run += dtot[t * 32 + j]; }
        int tot = run;
        for (int o = 1; o < 64; o <<= 1) {
            int x = __shfl_up(tot, o, 64);
            if (lane >= o) tot += x;
        }
        int excl = tot - run;
        #pragma unroll
        for (int j = 0; j < 32; j++) cnt[t * 32 + j] = excl + loc[j];
    }
    __syncthreads();
    for (int d = t; d < RB; d += BLK) cnt[d] += hist[b * RB + d];
    __syncthreads();
    int base = b * ELEMS;
    int myv = 0;
    #pragma unroll
    for (int r = 0; r < EPT; r++) {
        int i = base + r * BLK + t;
        if (i < NP) {
            int k = key0[i];
            if (k >= 0) {
                int pos = atomicAdd(&cnt[hashb(k)], 1);
                pairA[pos] = ((u64)(uint32_t)k << 32) | (uint32_t)i;
                myv++;
            }
        }
    }
    atomicAdd(&svld, myv);
    __syncthreads();
    if (t == 0) atomicAdd(&ctrl[1], svld);
}

// K4: hash-group + exact idx-rank -> compact 8B records. rank-0 (min idx =
// head) sets the flags byte. No pairA writeback.
__global__ void __launch_bounds__(512) vx_group(const u64* __restrict__ pairA,
                                                const int* __restrict__ dtot,
                                                u64* __restrict__ flags8,
                                                u64* __restrict__ recs) {
    __shared__ int htab[BCAP];          // keys -> fill ctr -> head-io (phased reuse)
    __shared__ int cnt[BCAP];           // per-slot count
    __shared__ int seg[BCAP];           // exclusive prefix (segment starts)
    __shared__ u64 sq[BCAP];            // multi-member segments (unordered)
    __shared__ int swp[8];              // per-wave scan partials
    __shared__ int sb[2];
    int t = threadIdx.x, d = blockIdx.x;
    if (t < 64) {                       // start = sum dtot[0..d)
        int acc = 0;
        for (int j = t; j < d; j += 64) acc += dtot[j];
        #pragma unroll
        for (int o = 32; o > 0; o >>= 1) acc += __shfl_down(acc, o, 64);
        if (t == 0) { sb[0] = acc; sb[1] = dtot[d]; }
    }
    for (int i = t; i < BCAP; i += 512) { htab[i] = -1; cnt[i] = 0; }
    __syncthreads();
    int start = sb[0], size = sb[1];
    if (size <= 0) return;              // uniform per block
    if (size > BCAP) size = BCAP;       // statistically unreachable guard
    bool a0 = t < size, a1 = t + 512 < size;
    u64 e0 = a0 ? pairA[start + t] : 0;
    u64 e1 = a1 ? pairA[start + 512 + t] : 0;
    int k0 = (int)(e0 >> 32), k1 = (int)(e1 >> 32);
    // hash-insert (open addressing; bounded probes: never hang)
    int s0 = 0, s1 = 0;
    if (a0) {
        s0 = (int)(((uint32_t)k0 * 0x85EBCA77u) >> 22);
        for (int it = 0; it < BCAP; ++it) {
            int old = atomicCAS(&htab[s0], -1, k0);
            if (old == -1 || old == k0) break;
            s0 = (s0 + 1) & (BCAP - 1);
        }
        atomicAdd(&cnt[s0], 1);
    }
    if (a1) {
        s1 = (int)(((uint32_t)k1 * 0x85EBCA77u) >> 22);
        for (int it = 0; it < BCAP; ++it) {
            int old = atomicCAS(&htab[s1], -1, k1);
            if (old == -1 || old == k1) break;
            s1 = (s1 + 1) & (BCAP - 1);
        }
        atomicAdd(&cnt[s1], 1);
    }
    __syncthreads();
    // exclusive scan of cnt[0..1023] -> seg (2 vals/thread, wave-scan + partials)
    int c0 = cnt[2 * t], c1 = cnt[2 * t + 1];
    int v = c0 + c1;
    int lane = t & 63, wv = t >> 6;
    int x = v;
    #pragma unroll
    for (int o = 1; o < 64; o <<= 1) {
        int y = __shfl_up(x, o, 64);
        if (lane >= o) x += y;
    }
    if (lane == 63) swp[wv] = x;
    // recycle htab as per-slot fill counters (all probes done)
    for (int i = t; i < BCAP; i += 512) htab[i] = 0;
    __syncthreads();
    if (t == 0) {
        int acc = 0;
        #pragma unroll
        for (int j = 0; j < 8; j++) { int tmp = swp[j]; swp[j] = acc; acc += tmp; }
    }
    __syncthreads();
    int excl = swp[wv] + x - v;
    seg[2 * t] = excl;
    seg[2 * t + 1] = excl + c0;
    __syncthreads();
    // scatter multi-member segments into sq (singletons skip: rank trivially 0)
    int st0 = 0, cn0 = 0, st1 = 0, cn1 = 0;
    if (a0) { st0 = seg[s0]; cn0 = cnt[s0]; if (cn0 > 1) sq[st0 + atomicAdd(&htab[s0], 1)] = e0; }
    if (a1) { st1 = seg[s1]; cn1 = cnt[s1]; if (cn1 > 1) sq[st1 + atomicAdd(&htab[s1], 1)] = e1; }
    __syncthreads();
    // exact rank within segment by idx; rank-0 publishes head io (htab reuse #2)
    int r0 = 0, r1 = 0;
    if (a0 && cn0 > 1) {
        uint32_t my = (uint32_t)e0;
        for (int q = st0; q < st0 + cn0; q++) r0 += ((uint32_t)sq[q] < my);
        if (r0 == 0) htab[s0] = (int)my;
    }
    if (a1 && cn1 > 1) {
        uint32_t my = (uint32_t)e1;
        for (int q = st1; q < st1 + cn1; q++) r1 += ((uint32_t)sq[q] < my);
        if (r1 == 0) htab[s1] = (int)my;
    }
    __syncthreads();
    unsigned char* flags = (unsigned char*)flags8;
    if (a0) {
        uint32_t my = (uint32_t)e0;
        u64 rec;
        if (r0 == 0) {
            flags[my] = 1;
            int g = cn0 < 15 ? cn0 : 15;
            rec = (1ull << 63) | ((u64)g << 52) | ((u64)(uint32_t)k0 << 25) | my;
        } else {
            uint32_t head = (uint32_t)htab[s0];
            int sl = r0 < 15 ? r0 : 15;
            rec = ((u64)sl << 50) | ((u64)head << 25) | my;
        }
        recs[start + st0 + r0] = rec;
    }
    if (a1) {
        uint32_t my = (uint32_t)e1;
        u64 rec;
        if (r1 == 0) {
            flags[my] = 1;
            int g = cn1 < 15 ? cn1 : 15;
            rec = (1ull << 63) | ((u64)g << 52) | ((u64)(uint32_t)k1 << 25) | my;
        } else {
            uint32_t head = (uint32_t)htab[s1];
            int sl = r1 < 15 ? r1 : 15;
            rec = ((u64)sl << 50) | ((u64)head << 25) | my;
        }
        recs[start + st1 + r1] = rec;
    }
}

// K5: per-block bytesum of flag words (publishes partials for wp2's walk).
__global__ void vx_wpA(const u64* __restrict__ flags8, int* __restrict__ wsum, int NP8) {
    __shared__ int s[BLK];
    int t = threadIdx.x, i = blockIdx.x * BLK + t;
    u64 wv = (i < NP8) ? flags8[i] : 0ull;
    s[t] = (int)((wv * BYTEMUL) >> 56);
    __syncthreads();
    for (int o = BLK / 2; o > 0; o >>= 1) { if (t < o) s[t] += s[t + o]; __syncthreads(); }
    if (t == 0) wsum[blockIdx.x] = s[0];
}

// K6: no-spin walk over wsum + in-block scan -> wpfx; last block publishes vnum.
// NEW: the unique thread whose word crosses flag-count MAXV emits io* (the io
// of the (MAXV+1)-th head) to ctrl[2] — final filters on head<io* before any
// gather (G >> MAXV: ~86% of records are dropped; this makes the drop free).
__global__ void vx_wp2(const u64* __restrict__ flags8, const int* __restrict__ wsum,
                       int* __restrict__ wpfx, int* __restrict__ ctrl,
                       float* __restrict__ out_vnum, int NP8) {
    __shared__ int s[BLK];
    __shared__ int eS;
    int t = threadIdx.x, b = blockIdx.x;
    if (t < 64) {
        int acc = 0;
        for (int base = 0; base < b; base += 64) {
            int idx = base + t;
            int v = (idx < b) ? wsum[idx] : 0;
            #pragma unroll
            for (int o = 32; o > 0; o >>= 1) v += __shfl_down(v, o, 64);
            acc += v;
        }
        if (t == 0) eS = acc;
    }
    int i = b * BLK + t;
    u64 wv = (i < NP8) ? flags8[i] : 0ull;
    int v = (int)((wv * BYTEMUL) >> 56);
    s[t] = v;
    __syncthreads();                        // also publishes eS
    for (int o = 1; o < BLK; o <<= 1) {
        int x = (t >= o) ? s[t - o] : 0; __syncthreads();
        s[t] += x; __syncthreads();
    }
    if (i < NP8) wpfx[i] = eS + s[t] - v;
    int incl = eS + s[t];                   // inclusive flag count through word i
    int exclw = incl - v;
    if (i < NP8 && exclw <= MAXV && incl > MAXV) {
        int need = MAXV + 1 - exclw;        // the (MAXV+1)-th flag is in this word
        int cum = 0;
        #pragma unroll
        for (int j = 0; j < 8; j++) {
            int f = (int)((wv >> (8 * j)) & 0xFF);
            cum += f;
            if (f && cum == need) ctrl[2] = i * 8 + j;      // unique writer
        }
    }
    if (b == gridDim.x - 1 && t == BLK - 1) {
        int G = eS + s[t];
        out_vnum[0] = (float)(G < MAXV ? G : MAXV);
    }
}

__device__ __forceinline__ int vox_rank(const u64* flags8, const int* wpfx, int io) {
    int w = io >> 3, b8 = io & 7;
    u64 below = flags8[w] & ((1ull << (8 * b8)) - 1ull);
    return wpfx[w] + (int)((below * BYTEMUL) >> 56);
}

// K7: streaming final — coalesced 8B record reads, no LDS, no barriers, no
// zeroing (prep's blind fill covers untouched bytes). head<io* register filter
// drops ~86% of records before the vox_rank gathers.
static constexpr int EPTF = 2;
__global__ void vx_final(const u64* __restrict__ recs, const u64* __restrict__ flags8,
                         const int* __restrict__ wpfx, const int* __restrict__ ctrl,
                         const float* __restrict__ pts, const float* __restrict__ vsz,
                         const float* __restrict__ crg, float* __restrict__ out, int NP) {
    int t = threadIdx.x, b = blockIdx.x;
    int nval = ctrl[1], io_star = ctrl[2];
    int gyd = (int)rintf((crg[4] - crg[1]) / vsz[1]);
    int gzd = (int)rintf((crg[5] - crg[2]) / vsz[2]);
    int base = b * (BLK * EPTF);
    #pragma unroll
    for (int r = 0; r < EPTF; r++) {
        int i = base + r * BLK + t;
        if (i >= nval) continue;
        u64 rec = recs[i];
        uint32_t my = (uint32_t)(rec & 0x1FFFFFFu);
        bool ishead = (rec >> 63) != 0;
        uint32_t head;
        int slot, k = 0, gsz = 0;
        if (ishead) {
            head = my; slot = 0;
            k = (int)((rec >> 25) & 0x7FFFFFFu);
            gsz = (int)((rec >> 52) & 15u);
        } else {
            head = (uint32_t)((rec >> 25) & 0x1FFFFFFu);
            slot = (int)((rec >> 50) & 15u);
        }
        if ((int)head >= io_star) continue;     // vid >= MAXV, no gathers needed
        // guards also cover poison reads in the (statistically unreachable)
        // BCAP-truncation case
        if (slot >= MAXP || my >= (uint32_t)NP || head >= (uint32_t)NP) continue;
        int vid = vox_rank(flags8, wpfx, (int)head);
        if (vid >= MAXV) continue;
        const float* src = pts + my * C;
        float* dst = out + (vid * MAXP + slot) * C;
        dst[0] = src[0]; dst[1] = src[1]; dst[2] = src[2]; dst[3] = src[3]; dst[4] = src[4];
        if (ishead) {
            int cz = k % gzd; int rr = k / gzd; int cy = rr % gyd; int cx = rr / gyd;
            out[CO_OFF + vid * 3 + 0] = (float)cz;
            out[CO_OFF + vid * 3 + 1] = (float)cy;
            out[CO_OFF + vid * 3 + 2] = (float)cx;
            out[NPV_OFF + vid] = (float)(gsz < MAXP ? gsz : MAXP);
        }
    }
}

extern "C" void kernel_launch(void* const* d_in, const int* in_sizes, int n_in,
                              void* d_out, int out_size, void* d_ws, size_t ws_size,
                              hipStream_t stream) {
    if (!d_out || !d_ws || n_in < 3) return;
    const float* pts = (const float*)d_in[0];
    const float* vsz = (const float*)d_in[1];
    const float* crg = (const float*)d_in[2];
    if (!pts || !vsz || !crg) return;
    const int NP  = in_sizes[0] / C;
    if (NP <= 0 || NP >= (1 << 25)) return;       // record io-field width
    const int NB  = (NP + ELEMS - 1) / ELEMS;     // 2048-elem blocks (586)
    const int NP8 = (NP + 7) / 8;                 // byte-flag u64 words (150000)
    const int NWB = (NP8 + BLK - 1) / BLK;        // wp blocks (586)
    const int NBF = (NP + BLK * EPTF - 1) / (BLK * EPTF);   // final blocks (2344)

    size_t need = (size_t)NP * 8ull                         // pairA
                + (size_t)NP * 8ull                         // recs
                + (size_t)NP * 4ull                         // key0
                + (size_t)RB * NB * 4ull                    // hist
                + (size_t)RB * 4ull                         // dtot
                + (size_t)NP8 * 8ull                        // flags8
                + (size_t)NP8 * 4ull                        // wpfx
                + (size_t)NWB * 4ull + 64ull;               // wsum + ctrl + pad
    if (ws_size < need) return;
    if ((size_t)out_size < (size_t)VN_OFF + 1) return;

    u64*   pairA  = (u64*)d_ws;
    u64*   recs   = pairA + NP;
    int*   key0   = (int*)(recs + NP);
    int*   hist   = key0 + NP;
    int*   dtot   = hist + (size_t)RB * NB;
    u64*   flags8 = (u64*)(dtot + RB);            // 8B-aligned
    int*   wpfx   = (int*)(flags8 + NP8);
    int*   wsum   = wpfx + NP8;
    int*   ctrl   = wsum + NWB;
    float* out    = (float*)d_out;

    vx_prep<<<NB, BLK, 0, stream>>>(pts, vsz, crg, key0, hist, flags8, ctrl, out, NP, NP8);
    vx_scanw<<<RB / 4, BLK, 0, stream>>>(hist, dtot, NB);
    vx_scat<<<NB, BLK, 0, stream>>>(key0, hist, dtot, pairA, ctrl, NP);
    vx_group<<<RB, 512, 0, stream>>>(pairA, dtot, flags8, recs);
    vx_wpA<<<NWB, BLK, 0, stream>>>(flags8, wsum, NP8);
    vx_wp2<<<NWB, BLK, 0, stream>>>(flags8, wsum, wpfx, ctrl, out + VN_OFF, NP8);
    vx_final<<<NBF, BLK, 0, stream>>>(recs, flags8, wpfx, ctrl, pts, vsz, crg, out, NP);
}